// Round 7
// baseline (209.203 us; speedup 1.0000x reference)
//
#include <hip/hip_runtime.h>
#include <hip/hip_bf16.h>

// IG-MSA (transposed channel attention), restructured:
//   K0: WvT/WLT = bf16 transposes of Wv/WL ([i=256][c=64]) for fragment loads
//   K1: XX[b] = x[b] @ x[b]^T   (64x64 Gram of channels over n=65536)
//   K2: (MFMA) finalize attention, fold Wp -> Mt3[b][ti=16][c=64][kk=16] bf16
//   K3: out = M^T @ ((Wv^T x) * (WL^T illu)) + bp, fully in-register chain:
//       mfma32 output (col=j) feeds mfma16 A-operand (row=j) directly --
//       no v transpose, no shared LDS, no __syncthreads.

#define NPOS 65536
#define CH 64
#define INNER 256

typedef __attribute__((ext_vector_type(8))) __bf16 bfrag;
typedef __attribute__((ext_vector_type(4))) float facc;
typedef __attribute__((ext_vector_type(4))) float fvec4;
typedef __attribute__((ext_vector_type(4))) short sh4;

__device__ __forceinline__ unsigned short f2bu(float f) {
  return __builtin_bit_cast(unsigned short, (__bf16)f);
}

#if __has_builtin(__builtin_amdgcn_mfma_f32_16x16x16bf16_1k)
__device__ __forceinline__ facc mfma16(sh4 a, sh4 b, facc c) {
  return __builtin_amdgcn_mfma_f32_16x16x16bf16_1k(a, b, c, 0, 0, 0);
}
#else
__device__ __forceinline__ facc mfma16(sh4 a, sh4 b, facc c) {
  asm("v_mfma_f32_16x16x16_bf16 %0, %1, %2, %0" : "+v"(c) : "v"(a), "v"(b));
  return c;
}
#endif

// swizzled byte address inside a 64x64 bf16 tile (row stride 128B)
#define SWA(row, colbyte) ((row) * 128 + ((colbyte) ^ (((row) & 7) << 4)))

// ---------------- K0: weight transpose to bf16 ----------------
__global__ __launch_bounds__(256) void k0_wt(const float* __restrict__ Wv,
                                             const float* __restrict__ WL,
                                             unsigned short* __restrict__ WvT,
                                             unsigned short* __restrict__ WLT) {
  int t = blockIdx.x * 256 + threadIdx.x;   // 16384 threads
  int c = t >> 8, i = t & 255;
  WvT[i * CH + c] = f2bu(Wv[c * INNER + i]);
  WLT[i * CH + c] = f2bu(WL[c * INNER + i]);
}

// ---------------- K1: channel Gram matrix ----------------
__global__ __launch_bounds__(256) void k1_xx(const float* __restrict__ x,
                                             float* __restrict__ xx) {
  const int b = blockIdx.y;
  const int wave = threadIdx.x >> 6, lane = threadIdx.x & 63;
  const int r = lane & 15, g = lane >> 4;
  const int gw = blockIdx.x * 4 + wave;   // 0..127 waves per b (gridDim.x == 32)
  const int per = NPOS / 128;             // 512 n per wave
  const size_t n0 = (size_t)gw * per;
  const float* xb = x + (size_t)b * CH * NPOS;

  facc acc[4][4] = {};

  for (int n = 0; n < per; n += 32) {
    bfrag fr[4];
#pragma unroll
    for (int t = 0; t < 4; ++t) {
      const float* p = xb + (size_t)(16 * t + r) * NPOS + n0 + n + g * 8;
      fvec4 lo = *(const fvec4*)p;
      fvec4 hi = *(const fvec4*)(p + 4);
      bfrag f;
#pragma unroll
      for (int e = 0; e < 4; ++e) { f[e] = (__bf16)lo[e]; f[e + 4] = (__bf16)hi[e]; }
      fr[t] = f;
    }
#pragma unroll
    for (int ti = 0; ti < 4; ++ti)
#pragma unroll
      for (int tj = 0; tj < 4; ++tj)
        acc[ti][tj] = __builtin_amdgcn_mfma_f32_16x16x32_bf16(fr[ti], fr[tj],
                                                              acc[ti][tj], 0, 0, 0);
  }

  __shared__ float red[4][4096];
  float* my = red[wave];
#pragma unroll
  for (int ti = 0; ti < 4; ++ti)
#pragma unroll
    for (int tj = 0; tj < 4; ++tj)
#pragma unroll
      for (int q = 0; q < 4; ++q)
        my[(16 * ti + g * 4 + q) * 64 + 16 * tj + r] = acc[ti][tj][q];
  __syncthreads();
  float* xxb = xx + (size_t)b * 4096;
  for (int i = threadIdx.x; i < 4096; i += 256)
    atomicAdd(xxb + i, red[0][i] + red[1][i] + red[2][i] + red[3][i]);
}

// ---------------- K2: MFMA finalize attention, fold Wp ----------------
__global__ __launch_bounds__(256) void k2_attn(
    const float* __restrict__ xx, const float* __restrict__ Wq,
    const float* __restrict__ Wk, const float* __restrict__ rescale,
    const float* __restrict__ Wp, unsigned short* __restrict__ Mt3) {
  const int b = blockIdx.x >> 2, h = blockIdx.x & 3;
  const int t = threadIdx.x;
  const int wave = t >> 6, lane = t & 63;
  const int r = lane & 15, g = lane >> 4;

  __shared__ __align__(16) char tXX[8192];  // XX rows, bf16, swizzled
  __shared__ __align__(16) char tWq[8192];  // Wq^T rows: tWq[e][c]
  __shared__ __align__(16) char tWk[8192];  // Wk^T rows
  __shared__ __align__(16) char tWp[8192];  // Wp^T rows: tWp[c'][d]
  __shared__ __align__(16) char tZq[8192];  // Zq rows
  __shared__ __align__(16) char tZk[8192];  // Zk rows
  __shared__ __align__(16) char tAt[8192];  // attn^T rows: tAt[e][d]
  __shared__ float gG[64][68];
  __shared__ float sMx[64][4], sSm[64][4];
  __shared__ float sNq[64], sNk[64];

  // ---- load XX (f32->bf16) and transposed weight slices ----
  const float* xxb = xx + (size_t)b * 4096;
#pragma unroll
  for (int rep = 0; rep < 16; ++rep) {
    int idx = rep * 256 + t;
    int row = idx >> 6, col = idx & 63;
    *(unsigned short*)(tXX + SWA(row, col * 2)) = f2bu(xxb[idx]);
    // Wq/Wk: element (c=row, e=col) -> tW*[e][c]
    float vq = Wq[row * INNER + h * 64 + col];
    float vk = Wk[row * INNER + h * 64 + col];
    *(unsigned short*)(tWq + SWA(col, row * 2)) = f2bu(vq);
    *(unsigned short*)(tWk + SWA(col, row * 2)) = f2bu(vk);
    // Wp: element (d=row, c2=col) -> tWp[c2][d]
    *(unsigned short*)(tWp + SWA(col, row * 2)) = f2bu(Wp[(h * 64 + row) * CH + col]);
  }
  __syncthreads();

  // ---- stage 2: Zq = Wq^T XX, Zk = Wk^T XX (uses XX symmetry for B) ----
  facc zq[4] = {}, zk[4] = {};
#pragma unroll
  for (int s = 0; s < 2; ++s) {
    bfrag aq = *(const bfrag*)(tWq + SWA(16 * wave + r, s * 64 + g * 16));
    bfrag ak = *(const bfrag*)(tWk + SWA(16 * wave + r, s * 64 + g * 16));
#pragma unroll
    for (int tj = 0; tj < 4; ++tj) {
      bfrag bx = *(const bfrag*)(tXX + SWA(16 * tj + r, s * 64 + g * 16));
      zq[tj] = __builtin_amdgcn_mfma_f32_16x16x32_bf16(aq, bx, zq[tj], 0, 0, 0);
      zk[tj] = __builtin_amdgcn_mfma_f32_16x16x32_bf16(ak, bx, zk[tj], 0, 0, 0);
    }
  }
#pragma unroll
  for (int tj = 0; tj < 4; ++tj)
#pragma unroll
    for (int q = 0; q < 4; ++q) {
      int row = 16 * wave + g * 4 + q, colb = (16 * tj + r) * 2;
      *(unsigned short*)(tZq + SWA(row, colb)) = f2bu(zq[tj][q]);
      *(unsigned short*)(tZk + SWA(row, colb)) = f2bu(zk[tj][q]);
    }
  __syncthreads();

  // ---- stage 4: G = Zk*Wq ; Q2 = Zq*Wq ; K2m = Zk*Wk (diag only used) ----
  facc ga[4] = {}, q2[4] = {}, k2[4] = {};
#pragma unroll
  for (int s = 0; s < 2; ++s) {
    bfrag azk = *(const bfrag*)(tZk + SWA(16 * wave + r, s * 64 + g * 16));
    bfrag azq = *(const bfrag*)(tZq + SWA(16 * wave + r, s * 64 + g * 16));
#pragma unroll
    for (int tj = 0; tj < 4; ++tj) {
      bfrag bq = *(const bfrag*)(tWq + SWA(16 * tj + r, s * 64 + g * 16));
      bfrag bk = *(const bfrag*)(tWk + SWA(16 * tj + r, s * 64 + g * 16));
      ga[tj] = __builtin_amdgcn_mfma_f32_16x16x32_bf16(azk, bq, ga[tj], 0, 0, 0);
      q2[tj] = __builtin_amdgcn_mfma_f32_16x16x32_bf16(azq, bq, q2[tj], 0, 0, 0);
      k2[tj] = __builtin_amdgcn_mfma_f32_16x16x32_bf16(azk, bk, k2[tj], 0, 0, 0);
    }
  }
#pragma unroll
  for (int tj = 0; tj < 4; ++tj)
#pragma unroll
    for (int q = 0; q < 4; ++q) {
      int row = 16 * wave + g * 4 + q, col = 16 * tj + r;
      gG[row][col] = ga[tj][q];
      if (row == col) { sNq[row] = q2[tj][q]; sNk[row] = k2[tj][q]; }
    }
  __syncthreads();

  if (t < 64) {
    sNq[t] = 1.f / fmaxf(sqrtf(sNq[t]), 1e-12f);
    sNk[t] = rescale[h] / fmaxf(sqrtf(sNk[t]), 1e-12f);
  }
  __syncthreads();

  // ---- softmax over e per row d (4 threads per row) ----
  {
    const int d = t >> 2, p = t & 3;
    const float ik = sNk[d];
    float le[16];
    float mx = -1e30f;
#pragma unroll
    for (int j = 0; j < 16; ++j) {
      float v = gG[d][16 * p + j] * ik * sNq[16 * p + j];
      le[j] = v; mx = fmaxf(mx, v);
    }
    sMx[d][p] = mx;
    __syncthreads();
    mx = fmaxf(fmaxf(sMx[d][0], sMx[d][1]), fmaxf(sMx[d][2], sMx[d][3]));
    float sm = 0.f;
#pragma unroll
    for (int j = 0; j < 16; ++j) { le[j] = __expf(le[j] - mx); sm += le[j]; }
    sSm[d][p] = sm;
    __syncthreads();
    sm = sSm[d][0] + sSm[d][1] + sSm[d][2] + sSm[d][3];
    const float inv = 1.f / sm;
#pragma unroll
    for (int j = 0; j < 16; ++j) {
      int e = 16 * p + j;
      *(unsigned short*)(tAt + SWA(e, d * 2)) = f2bu(le[j] * inv);
    }
  }
  __syncthreads();

  // ---- stage 6: M = attn^T * Wp ; write Mt3[b][ti][c][kk] bf16 ----
  facc m[4] = {};
#pragma unroll
  for (int s = 0; s < 2; ++s) {
    bfrag aa = *(const bfrag*)(tAt + SWA(16 * wave + r, s * 64 + g * 16));
#pragma unroll
    for (int tj = 0; tj < 4; ++tj) {
      bfrag bw = *(const bfrag*)(tWp + SWA(16 * tj + r, s * 64 + g * 16));
      m[tj] = __builtin_amdgcn_mfma_f32_16x16x32_bf16(aa, bw, m[tj], 0, 0, 0);
    }
  }
#pragma unroll
  for (int tj = 0; tj < 4; ++tj)
#pragma unroll
    for (int q = 0; q < 4; ++q) {
      int i_glob = h * 64 + 16 * wave + g * 4 + q;   // global inner index
      int c2 = 16 * tj + r;
      Mt3[((size_t)b * 16 + (i_glob >> 4)) * 1024 + c2 * 16 + (i_glob & 15)] =
          f2bu(m[tj][q]);
    }
}

// ---------------- K3: gated V + folded output projection ----------------
// Per-wave independent j-tiles; mfma32 -> mfma16 in-register chain; no
// __syncthreads (each wave stages its own private LDS slice).
__global__ __launch_bounds__(256) void k3_out(
    const float* __restrict__ x, const float* __restrict__ illu,
    const unsigned short* __restrict__ WvT, const unsigned short* __restrict__ WLT,
    const unsigned short* __restrict__ Mt3, const float* __restrict__ bp,
    float* __restrict__ out) {
  const int b = blockIdx.y;
  const int wave = threadIdx.x >> 6, lane = threadIdx.x & 63;
  const int r = lane & 15, g = lane >> 4;
  const int n0 = blockIdx.x * 256 + wave * 64;   // wave's 64-n span

  __shared__ __align__(16) char sst[4][2][2048];  // per-wave [16 j][128B] x,illu
  char* myx = sst[wave][0];
  char* myi = sst[wave][1];

  const float* xb = x + (size_t)b * CH * NPOS + (size_t)lane * NPOS;   // lane = c
  const float* ib = illu + (size_t)b * CH * NPOS + (size_t)lane * NPOS;
  float* ob = out + (size_t)b * CH * NPOS;
  const unsigned short* mt = Mt3 + (size_t)b * 16384;

  float bias[4];
#pragma unroll
  for (int ct = 0; ct < 4; ++ct) bias[ct] = bp[ct * 16 + r];

  for (int t = 0; t < 4; ++t) {       // j-tiles of 16 n
    const int nb = n0 + t * 16;
    // ---- stage this wave's [16 j][64 c] slice (lane = c) ----
    {
      fvec4 xv[4], iv[4];
#pragma unroll
      for (int p = 0; p < 4; ++p) {
        xv[p] = *(const fvec4*)(xb + nb + p * 4);
        iv[p] = *(const fvec4*)(ib + nb + p * 4);
      }
#pragma unroll
      for (int j = 0; j < 16; ++j) {
        const int byte = (lane * 2) ^ ((j & 7) << 4);
        *(unsigned short*)(myx + j * 128 + byte) = f2bu(xv[j >> 2][j & 3]);
        *(unsigned short*)(myi + j * 128 + byte) = f2bu(iv[j >> 2][j & 3]);
      }
    }
    // ---- fragments (same-wave LDS dependency; compiler inserts lgkmcnt) ----
    bfrag xB[2], iB[2];
#pragma unroll
    for (int s = 0; s < 2; ++s) {
      const int byte = (s * 64 + g * 16) ^ ((r & 7) << 4);
      xB[s] = *(const bfrag*)(myx + r * 128 + byte);
      iB[s] = *(const bfrag*)(myi + r * 128 + byte);
    }

    facc acc[4] = {};   // ct = c-out tiles of 16
#pragma unroll 4
    for (int ti = 0; ti < 16; ++ti) {
      const int irow = ti * 16 + r;
      bfrag wv0 = *(const bfrag*)(WvT + irow * CH + g * 8);
      bfrag wv1 = *(const bfrag*)(WvT + irow * CH + 32 + g * 8);
      bfrag wl0 = *(const bfrag*)(WLT + irow * CH + g * 8);
      bfrag wl1 = *(const bfrag*)(WLT + irow * CH + 32 + g * 8);
      facc av = {}, gv = {};
      av = __builtin_amdgcn_mfma_f32_16x16x32_bf16(wv0, xB[0], av, 0, 0, 0);
      av = __builtin_amdgcn_mfma_f32_16x16x32_bf16(wv1, xB[1], av, 0, 0, 0);
      gv = __builtin_amdgcn_mfma_f32_16x16x32_bf16(wl0, iB[0], gv, 0, 0, 0);
      gv = __builtin_amdgcn_mfma_f32_16x16x32_bf16(wl1, iB[1], gv, 0, 0, 0);
      // gate + pack: lane holds v[i=ti*16+g*4+e][j=r] -> exactly the A-frag
      // of mfma_16x16x16 (row=r=j, k=g*4+e within this ti's 16-i window)
      sh4 a2;
#pragma unroll
      for (int e = 0; e < 4; ++e)
        a2[e] = (short)f2bu(av[e] * gv[e]);
      const unsigned short* mrow = mt + ti * 1024 + g * 4;
#pragma unroll
      for (int ct = 0; ct < 4; ++ct) {
        sh4 mb = *(const sh4*)(mrow + (ct * 16 + r) * 16);
        acc[ct] = mfma16(a2, mb, acc[ct]);
      }
    }
    // ---- store: lane holds out[c=ct*16+r][j=g*4+q], q contiguous ----
#pragma unroll
    for (int ct = 0; ct < 4; ++ct) {
      fvec4 o;
#pragma unroll
      for (int q = 0; q < 4; ++q) o[q] = acc[ct][q] + bias[ct];
      *(fvec4*)(ob + (size_t)(ct * 16 + r) * NPOS + nb + g * 4) = o;
    }
  }
}

extern "C" void kernel_launch(void* const* d_in, const int* in_sizes, int n_in,
                              void* d_out, int out_size, void* d_ws, size_t ws_size,
                              hipStream_t stream) {
  (void)in_sizes; (void)n_in; (void)out_size; (void)ws_size;
  const float* x    = (const float*)d_in[0];
  const float* illu = (const float*)d_in[1];
  const float* Wq   = (const float*)d_in[2];
  const float* Wk   = (const float*)d_in[3];
  const float* Wv   = (const float*)d_in[4];
  const float* WL   = (const float*)d_in[5];
  const float* rsc  = (const float*)d_in[6];
  const float* Wp   = (const float*)d_in[7];
  const float* bp   = (const float*)d_in[8];
  float* out = (float*)d_out;

  float* xxws = (float*)d_ws;                                        // 64 KB
  unsigned short* Mt3 = (unsigned short*)((char*)d_ws + 65536);      // 128 KB
  unsigned short* WvT = (unsigned short*)((char*)d_ws + 65536 + 131072); // 32 KB
  unsigned short* WLT = WvT + INNER * CH;                            // 32 KB

  hipMemsetAsync(d_ws, 0, (size_t)4 * 4096 * sizeof(float), stream);
  hipLaunchKernelGGL(k0_wt, dim3(64), dim3(256), 0, stream, Wv, WL, WvT, WLT);
  hipLaunchKernelGGL(k1_xx, dim3(32, 4), dim3(256), 0, stream, x, xxws);
  hipLaunchKernelGGL(k2_attn, dim3(16), dim3(256), 0, stream, xxws, Wq, Wk, rsc, Wp, Mt3);
  hipLaunchKernelGGL(k3_out, dim3(256, 4), dim3(256), 0, stream, x, illu, WvT, WLT, Mt3, bp, out);
}

// Round 8
// 155.657 us; speedup vs baseline: 1.3440x; 1.3440x over previous
//
#include <hip/hip_runtime.h>
#include <hip/hip_bf16.h>

// IG-MSA (transposed channel attention), restructured:
//   K0: WvT/WLT = bf16 transposes of Wv/WL ([i=256][c=64]) for fragment loads
//   K1: XX[b] = x[b] @ x[b]^T   (64x64 Gram of channels over n=65536)
//   K2: (MFMA) Zq=Wq^T XX, Zk=Wk^T XX; G=Zk Wq; norms=diag(Zq Wq / Zk Wk);
//       softmax; M = attn^T Wp  -> Mt[b, c', i] bf16
//   K3: out[b,c,n] = M^T @ ((Wv^T x) * (WL^T illu)) + bp   (MFMA, bf16)
//       round 8: round-5 structure + dbuf'd x/illu staging with SHORT-lived
//       split prefetch (x then illu), chunk stagger, b64 v-writes.

#define NPOS 65536
#define CH 64
#define INNER 256

typedef __attribute__((ext_vector_type(8))) __bf16 bfrag;
typedef __attribute__((ext_vector_type(4))) float facc;
typedef __attribute__((ext_vector_type(4))) float fvec4;

__device__ __forceinline__ unsigned short f2bu(float f) {
  return __builtin_bit_cast(unsigned short, (__bf16)f);
}

// swizzled byte address inside a 64x64 bf16 tile (row stride 128B)
#define SWA(row, colbyte) ((row) * 128 + ((colbyte) ^ (((row) & 7) << 4)))

// ---------------- K0: weight transpose to bf16 ----------------
__global__ __launch_bounds__(256) void k0_wt(const float* __restrict__ Wv,
                                             const float* __restrict__ WL,
                                             unsigned short* __restrict__ WvT,
                                             unsigned short* __restrict__ WLT) {
  int t = blockIdx.x * 256 + threadIdx.x;   // 16384 threads
  int c = t >> 8, i = t & 255;
  WvT[i * CH + c] = f2bu(Wv[c * INNER + i]);
  WLT[i * CH + c] = f2bu(WL[c * INNER + i]);
}

// ---------------- K1: channel Gram matrix ----------------
__global__ __launch_bounds__(256) void k1_xx(const float* __restrict__ x,
                                             float* __restrict__ xx) {
  const int b = blockIdx.y;
  const int wave = threadIdx.x >> 6, lane = threadIdx.x & 63;
  const int r = lane & 15, g = lane >> 4;
  const int gw = blockIdx.x * 4 + wave;   // 0..127 waves per b (gridDim.x == 32)
  const int per = NPOS / 128;             // 512 n per wave
  const size_t n0 = (size_t)gw * per;
  const float* xb = x + (size_t)b * CH * NPOS;

  facc acc[4][4] = {};

  for (int n = 0; n < per; n += 32) {
    bfrag fr[4];
#pragma unroll
    for (int t = 0; t < 4; ++t) {
      const float* p = xb + (size_t)(16 * t + r) * NPOS + n0 + n + g * 8;
      fvec4 lo = *(const fvec4*)p;
      fvec4 hi = *(const fvec4*)(p + 4);
      bfrag f;
#pragma unroll
      for (int e = 0; e < 4; ++e) { f[e] = (__bf16)lo[e]; f[e + 4] = (__bf16)hi[e]; }
      fr[t] = f;
    }
#pragma unroll
    for (int ti = 0; ti < 4; ++ti)
#pragma unroll
      for (int tj = 0; tj < 4; ++tj)
        acc[ti][tj] = __builtin_amdgcn_mfma_f32_16x16x32_bf16(fr[ti], fr[tj],
                                                              acc[ti][tj], 0, 0, 0);
  }

  __shared__ float red[4][4096];
  float* my = red[wave];
#pragma unroll
  for (int ti = 0; ti < 4; ++ti)
#pragma unroll
    for (int tj = 0; tj < 4; ++tj)
#pragma unroll
      for (int q = 0; q < 4; ++q)
        my[(16 * ti + g * 4 + q) * 64 + 16 * tj + r] = acc[ti][tj][q];
  __syncthreads();
  float* xxb = xx + (size_t)b * 4096;
  for (int i = threadIdx.x; i < 4096; i += 256)
    atomicAdd(xxb + i, red[0][i] + red[1][i] + red[2][i] + red[3][i]);
}

// ---------------- K2: MFMA finalize attention, fold Wp ----------------
__global__ __launch_bounds__(256) void k2_attn(
    const float* __restrict__ xx, const float* __restrict__ Wq,
    const float* __restrict__ Wk, const float* __restrict__ rescale,
    const float* __restrict__ Wp, unsigned short* __restrict__ Mt) {
  const int b = blockIdx.x >> 2, h = blockIdx.x & 3;
  const int t = threadIdx.x;
  const int wave = t >> 6, lane = t & 63;
  const int r = lane & 15, g = lane >> 4;

  __shared__ __align__(16) char tXX[8192];  // XX rows, bf16, swizzled
  __shared__ __align__(16) char tWq[8192];  // Wq^T rows: tWq[e][c]
  __shared__ __align__(16) char tWk[8192];  // Wk^T rows
  __shared__ __align__(16) char tWp[8192];  // Wp^T rows: tWp[c'][d]
  __shared__ __align__(16) char tZq[8192];  // Zq rows
  __shared__ __align__(16) char tZk[8192];  // Zk rows
  __shared__ __align__(16) char tAt[8192];  // attn^T rows: tAt[e][d]
  __shared__ float gG[64][68];
  __shared__ float sMx[64][4], sSm[64][4];
  __shared__ float sNq[64], sNk[64];

  // ---- load XX (f32->bf16) and transposed weight slices ----
  const float* xxb = xx + (size_t)b * 4096;
#pragma unroll
  for (int rep = 0; rep < 16; ++rep) {
    int idx = rep * 256 + t;
    int row = idx >> 6, col = idx & 63;
    *(unsigned short*)(tXX + SWA(row, col * 2)) = f2bu(xxb[idx]);
    float vq = Wq[row * INNER + h * 64 + col];
    float vk = Wk[row * INNER + h * 64 + col];
    *(unsigned short*)(tWq + SWA(col, row * 2)) = f2bu(vq);
    *(unsigned short*)(tWk + SWA(col, row * 2)) = f2bu(vk);
    *(unsigned short*)(tWp + SWA(col, row * 2)) = f2bu(Wp[(h * 64 + row) * CH + col]);
  }
  __syncthreads();

  // ---- stage 2: Zq = Wq^T XX, Zk = Wk^T XX (uses XX symmetry for B) ----
  facc zq[4] = {}, zk[4] = {};
#pragma unroll
  for (int s = 0; s < 2; ++s) {
    bfrag aq = *(const bfrag*)(tWq + SWA(16 * wave + r, s * 64 + g * 16));
    bfrag ak = *(const bfrag*)(tWk + SWA(16 * wave + r, s * 64 + g * 16));
#pragma unroll
    for (int tj = 0; tj < 4; ++tj) {
      bfrag bx = *(const bfrag*)(tXX + SWA(16 * tj + r, s * 64 + g * 16));
      zq[tj] = __builtin_amdgcn_mfma_f32_16x16x32_bf16(aq, bx, zq[tj], 0, 0, 0);
      zk[tj] = __builtin_amdgcn_mfma_f32_16x16x32_bf16(ak, bx, zk[tj], 0, 0, 0);
    }
  }
#pragma unroll
  for (int tj = 0; tj < 4; ++tj)
#pragma unroll
    for (int q = 0; q < 4; ++q) {
      int row = 16 * wave + g * 4 + q, colb = (16 * tj + r) * 2;
      *(unsigned short*)(tZq + SWA(row, colb)) = f2bu(zq[tj][q]);
      *(unsigned short*)(tZk + SWA(row, colb)) = f2bu(zk[tj][q]);
    }
  __syncthreads();

  // ---- stage 4: G = Zk*Wq ; Q2 = Zq*Wq ; K2m = Zk*Wk (diag only used) ----
  facc ga[4] = {}, q2[4] = {}, k2[4] = {};
#pragma unroll
  for (int s = 0; s < 2; ++s) {
    bfrag azk = *(const bfrag*)(tZk + SWA(16 * wave + r, s * 64 + g * 16));
    bfrag azq = *(const bfrag*)(tZq + SWA(16 * wave + r, s * 64 + g * 16));
#pragma unroll
    for (int tj = 0; tj < 4; ++tj) {
      bfrag bq = *(const bfrag*)(tWq + SWA(16 * tj + r, s * 64 + g * 16));
      bfrag bk = *(const bfrag*)(tWk + SWA(16 * tj + r, s * 64 + g * 16));
      ga[tj] = __builtin_amdgcn_mfma_f32_16x16x32_bf16(azk, bq, ga[tj], 0, 0, 0);
      q2[tj] = __builtin_amdgcn_mfma_f32_16x16x32_bf16(azq, bq, q2[tj], 0, 0, 0);
      k2[tj] = __builtin_amdgcn_mfma_f32_16x16x32_bf16(azk, bk, k2[tj], 0, 0, 0);
    }
  }
#pragma unroll
  for (int tj = 0; tj < 4; ++tj)
#pragma unroll
    for (int q = 0; q < 4; ++q) {
      int row = 16 * wave + g * 4 + q, col = 16 * tj + r;
      gG[row][col] = ga[tj][q];
      if (row == col) { sNq[row] = q2[tj][q]; sNk[row] = k2[tj][q]; }
    }
  __syncthreads();

  if (t < 64) {
    sNq[t] = 1.f / fmaxf(sqrtf(sNq[t]), 1e-12f);
    sNk[t] = rescale[h] / fmaxf(sqrtf(sNk[t]), 1e-12f);
  }
  __syncthreads();

  // ---- softmax over e per row d (4 threads per row) ----
  {
    const int d = t >> 2, p = t & 3;
    const float ik = sNk[d];
    float le[16];
    float mx = -1e30f;
#pragma unroll
    for (int j = 0; j < 16; ++j) {
      float v = gG[d][16 * p + j] * ik * sNq[16 * p + j];
      le[j] = v; mx = fmaxf(mx, v);
    }
    sMx[d][p] = mx;
    __syncthreads();
    mx = fmaxf(fmaxf(sMx[d][0], sMx[d][1]), fmaxf(sMx[d][2], sMx[d][3]));
    float sm = 0.f;
#pragma unroll
    for (int j = 0; j < 16; ++j) { le[j] = __expf(le[j] - mx); sm += le[j]; }
    sSm[d][p] = sm;
    __syncthreads();
    sm = sSm[d][0] + sSm[d][1] + sSm[d][2] + sSm[d][3];
    const float inv = 1.f / sm;
#pragma unroll
    for (int j = 0; j < 16; ++j) {
      int e = 16 * p + j;
      *(unsigned short*)(tAt + SWA(e, d * 2)) = f2bu(le[j] * inv);
    }
  }
  __syncthreads();

  // ---- stage 6: M = attn^T * Wp ; write Mt[b][c'][h*64+e] bf16 ----
  facc m[4] = {};
#pragma unroll
  for (int s = 0; s < 2; ++s) {
    bfrag aa = *(const bfrag*)(tAt + SWA(16 * wave + r, s * 64 + g * 16));
#pragma unroll
    for (int tj = 0; tj < 4; ++tj) {
      bfrag bw = *(const bfrag*)(tWp + SWA(16 * tj + r, s * 64 + g * 16));
      m[tj] = __builtin_amdgcn_mfma_f32_16x16x32_bf16(aa, bw, m[tj], 0, 0, 0);
    }
  }
#pragma unroll
  for (int tj = 0; tj < 4; ++tj)
#pragma unroll
    for (int q = 0; q < 4; ++q) {
      int e = 16 * wave + g * 4 + q, c2 = 16 * tj + r;
      Mt[((size_t)(b * CH + c2)) * INNER + h * 64 + e] = f2bu(m[tj][q]);
    }
}

// ---------------- K3: gated V + folded output projection ----------------
// Round-5 structure + dbuf'd staging with short-lived split prefetch:
//   LOADX(next) at chunk top -> WRITEX after sub1 (x regs live 2 subs)
//   LOADI(next) after sub1   -> WRITEI after sub3 (illu regs live 2 subs)
// Chunk order staggered per block to break the stage convoy.
__global__ __launch_bounds__(256, 3) void k3_out(
    const float* __restrict__ x, const float* __restrict__ illu,
    const unsigned short* __restrict__ WvT, const unsigned short* __restrict__ WLT,
    const unsigned short* __restrict__ Mt, const float* __restrict__ bp,
    float* __restrict__ out) {
  const int b = blockIdx.y;
  const int wave = threadIdx.x >> 6, lane = threadIdx.x & 63;
  const int r = lane & 15, g = lane >> 4;
  const int n0 = blockIdx.x * 256;          // gridDim.x == 256
  const int stag = (blockIdx.x >> 3) & 3;   // chunk-order stagger

  __shared__ __align__(16) char lxs[2][8192];  // x tile [j=64][c=64] bf16, swz
  __shared__ __align__(16) char lis[2][8192];  // illu tile
  __shared__ __align__(16) char lvs[2][8192];  // v tile [j=16][i=256] bf16

  // --- per-wave weight fragments (A-operands), 16B vector loads ---
  bfrag wvA[4][2], wlA[4][2], mtA[8];
#pragma unroll
  for (int ti = 0; ti < 4; ++ti) {
    const int i = wave * 64 + ti * 16 + r;
#pragma unroll
    for (int s = 0; s < 2; ++s) {
      wvA[ti][s] = *(const bfrag*)(WvT + i * CH + s * 32 + g * 8);
      wlA[ti][s] = *(const bfrag*)(WLT + i * CH + s * 32 + g * 8);
    }
  }
#pragma unroll
  for (int s8 = 0; s8 < 8; ++s8)
    mtA[s8] = *(const bfrag*)(Mt + ((size_t)(b * CH + wave * 16 + r)) * INNER + s8 * 32 + g * 8);
  float bcol[4];
#pragma unroll
  for (int q = 0; q < 4; ++q) bcol[q] = bp[wave * 16 + g * 4 + q];

  const float* xb = x + (size_t)b * CH * NPOS;
  const float* ib = illu + (size_t)b * CH * NPOS;
  float* ob = out + (size_t)b * CH * NPOS;

  const int sc2 = threadIdx.x >> 3;        // 0..31 c-pair
  const int sjo = (threadIdx.x & 7) * 8;   // j offset within 64-chunk

  fvec4 xa0, xa1, xr0, xr1, ia0, ia1, ir0, ir1;

#define LOADX(NB)                                                          \
  {                                                                        \
    const float* p = xb + (size_t)(2 * sc2) * NPOS + (NB) + sjo;           \
    xa0 = *(const fvec4*)p;          xa1 = *(const fvec4*)(p + 4);         \
    xr0 = *(const fvec4*)(p + NPOS); xr1 = *(const fvec4*)(p + NPOS + 4);  \
  }
#define LOADI(NB)                                                          \
  {                                                                        \
    const float* p = ib + (size_t)(2 * sc2) * NPOS + (NB) + sjo;           \
    ia0 = *(const fvec4*)p;          ia1 = *(const fvec4*)(p + 4);         \
    ir0 = *(const fvec4*)(p + NPOS); ir1 = *(const fvec4*)(p + NPOS + 4);  \
  }
#define WRITEX(BUF)                                                        \
  {                                                                        \
    _Pragma("unroll")                                                      \
    for (int jj = 0; jj < 8; ++jj) {                                       \
      const int j = sjo + jj;                                              \
      const int byte = (sc2 * 4) ^ (((j ^ (j >> 3)) & 7) << 4);            \
      float v0 = jj < 4 ? xa0[jj & 3] : xa1[jj & 3];                       \
      float v1 = jj < 4 ? xr0[jj & 3] : xr1[jj & 3];                       \
      *(unsigned int*)(lxs[BUF] + j * 128 + byte) =                        \
          (unsigned int)f2bu(v0) | ((unsigned int)f2bu(v1) << 16);         \
    }                                                                      \
  }
#define WRITEI(BUF)                                                        \
  {                                                                        \
    _Pragma("unroll")                                                      \
    for (int jj = 0; jj < 8; ++jj) {                                       \
      const int j = sjo + jj;                                              \
      const int byte = (sc2 * 4) ^ (((j ^ (j >> 3)) & 7) << 4);            \
      float v0 = jj < 4 ? ia0[jj & 3] : ia1[jj & 3];                       \
      float v1 = jj < 4 ? ir0[jj & 3] : ir1[jj & 3];                       \
      *(unsigned int*)(lis[BUF] + j * 128 + byte) =                        \
          (unsigned int)f2bu(v0) | ((unsigned int)f2bu(v1) << 16);         \
    }                                                                      \
  }

  auto subbody = [&](int sub, int cb, int nbase) {
    const int vb = sub & 1;
    const int j0 = sub * 16;
    const int j = j0 + r;
    const int swv = ((j ^ (j >> 3)) & 7) << 4;
    bfrag xB[2], iB[2];
#pragma unroll
    for (int s = 0; s < 2; ++s) {
      const int byte = (s * 64 + g * 16) ^ swv;
      xB[s] = *(const bfrag*)(lxs[cb] + j * 128 + byte);
      iB[s] = *(const bfrag*)(lis[cb] + j * 128 + byte);
    }
    facc av[4] = {}, gv[4] = {};
    __builtin_amdgcn_s_setprio(1);
#pragma unroll
    for (int ti = 0; ti < 4; ++ti) {
#pragma unroll
      for (int s = 0; s < 2; ++s) {
        av[ti] = __builtin_amdgcn_mfma_f32_16x16x32_bf16(wvA[ti][s], xB[s], av[ti], 0, 0, 0);
        gv[ti] = __builtin_amdgcn_mfma_f32_16x16x32_bf16(wlA[ti][s], iB[s], gv[ti], 0, 0, 0);
      }
    }
    __builtin_amdgcn_s_setprio(0);
    // gate + packed b64 write of v tile (rows i..i+3 contiguous, col j = r)
#pragma unroll
    for (int ti = 0; ti < 4; ++ti) {
      const float v0 = av[ti][0] * gv[ti][0], v1 = av[ti][1] * gv[ti][1];
      const float v2 = av[ti][2] * gv[ti][2], v3 = av[ti][3] * gv[ti][3];
      const int i = wave * 64 + ti * 16 + g * 4;
      const int sw = (r & 7) << 4;
      unsigned long long pk =
          (unsigned long long)((unsigned int)f2bu(v0) | ((unsigned int)f2bu(v1) << 16)) |
          ((unsigned long long)((unsigned int)f2bu(v2) | ((unsigned int)f2bu(v3) << 16)) << 32);
      *(unsigned long long*)(lvs[vb] + r * 512 + ((i * 2) ^ sw)) = pk;
    }
    __syncthreads();
    // out tile: M^T @ v  (K = i = 256)
    facc ov = {0.f, 0.f, 0.f, 0.f};
    __builtin_amdgcn_s_setprio(1);
#pragma unroll
    for (int s8 = 0; s8 < 8; ++s8) {
      const int byte = (s8 * 64 + g * 16) ^ ((r & 7) << 4);
      bfrag vB = *(const bfrag*)(lvs[vb] + r * 512 + byte);
      ov = __builtin_amdgcn_mfma_f32_16x16x32_bf16(mtA[s8], vB, ov, 0, 0, 0);
    }
    __builtin_amdgcn_s_setprio(0);
#pragma unroll
    for (int q = 0; q < 4; ++q)
      ob[(size_t)(wave * 16 + g * 4 + q) * NPOS + nbase + j0 + r] = ov[q] + bcol[q];
  };

  // prologue: stage first chunk into buf 0
  LOADX(n0 + stag * 64); WRITEX(0);
  LOADI(n0 + stag * 64); WRITEI(0);
  __syncthreads();

  for (int cc = 0; cc < 4; ++cc) {
    const int cb = cc & 1;
    const int nbase = n0 + (((cc + stag) & 3) << 6);
    const int nnext = n0 + (((cc + 1 + stag) & 3) << 6);
    if (cc < 3) LOADX(nnext);           // in flight across subs 0-1
    subbody(0, cb, nbase);
    subbody(1, cb, nbase);
    if (cc < 3) { WRITEX(cb ^ 1); LOADI(nnext); }   // illu in flight subs 2-3
    subbody(2, cb, nbase);
    subbody(3, cb, nbase);
    if (cc < 3) WRITEI(cb ^ 1);
    __syncthreads();
  }
#undef LOADX
#undef LOADI
#undef WRITEX
#undef WRITEI
}

extern "C" void kernel_launch(void* const* d_in, const int* in_sizes, int n_in,
                              void* d_out, int out_size, void* d_ws, size_t ws_size,
                              hipStream_t stream) {
  (void)in_sizes; (void)n_in; (void)out_size; (void)ws_size;
  const float* x    = (const float*)d_in[0];
  const float* illu = (const float*)d_in[1];
  const float* Wq   = (const float*)d_in[2];
  const float* Wk   = (const float*)d_in[3];
  const float* Wv   = (const float*)d_in[4];
  const float* WL   = (const float*)d_in[5];
  const float* rsc  = (const float*)d_in[6];
  const float* Wp   = (const float*)d_in[7];
  const float* bp   = (const float*)d_in[8];
  float* out = (float*)d_out;

  float* xxws = (float*)d_ws;                                        // 64 KB
  unsigned short* Mt  = (unsigned short*)((char*)d_ws + 65536);      // 128 KB
  unsigned short* WvT = (unsigned short*)((char*)d_ws + 65536 + 131072); // 32 KB
  unsigned short* WLT = WvT + INNER * CH;                            // 32 KB

  hipMemsetAsync(d_ws, 0, (size_t)4 * 4096 * sizeof(float), stream);
  hipLaunchKernelGGL(k0_wt, dim3(64), dim3(256), 0, stream, Wv, WL, WvT, WLT);
  hipLaunchKernelGGL(k1_xx, dim3(32, 4), dim3(256), 0, stream, x, xxws);
  hipLaunchKernelGGL(k2_attn, dim3(16), dim3(256), 0, stream, xxws, Wq, Wk, rsc, Wp, Mt);
  hipLaunchKernelGGL(k3_out, dim3(256, 4), dim3(256), 0, stream, x, illu, WvT, WLT, Mt, bp, out);
}

// Round 10
// 85.479 us; speedup vs baseline: 2.4474x; 1.8210x over previous
//
#include <hip/hip_runtime.h>
#include <hip/hip_bf16.h>

// IG-MSA (transposed channel attention), restructured:
//   K0: WvT/WLT = bf16 transposes of Wv/WL ([i=256][c=64]) for fragment loads
//   K1: XX[b] = x[b] @ x[b]^T   (64x64 Gram of channels over n=65536)
//   K2: (MFMA) finalize attention, fold Wp -> Mt[b, c', i] bf16
//   K3: out[b,c,n] = M^T @ ((Wv^T x) * (WL^T illu)) + bp   (MFMA, bf16)
//       round 10: round-9 async global_load_lds staging, with the race fixed:
//       every waitcnt+barrier fused into ONE asm volatile w/ "memory" clobber
//       so no LDS op can be scheduled between the wait and the barrier.

#define NPOS 65536
#define CH 64
#define INNER 256

typedef __attribute__((ext_vector_type(8))) __bf16 bfrag;
typedef __attribute__((ext_vector_type(4))) float facc;
typedef __attribute__((ext_vector_type(4))) float fvec4;

typedef const __attribute__((address_space(1))) unsigned int guint;
typedef __attribute__((address_space(3))) unsigned int luint;

__device__ __forceinline__ unsigned short f2bu(float f) {
  return __builtin_bit_cast(unsigned short, (__bf16)f);
}

// swizzled byte address inside a 64x64 bf16 tile (row stride 128B)
#define SWA(row, colbyte) ((row) * 128 + ((colbyte) ^ (((row) & 7) << 4)))

// fused wait+barrier: single opaque asm, nothing crosses it at compile time
#define BAR_VM4()  asm volatile("s_waitcnt vmcnt(4)\n\ts_barrier" ::: "memory")
#define BAR_VM0()  asm volatile("s_waitcnt vmcnt(0)\n\ts_barrier" ::: "memory")
#define BAR_LGKM() asm volatile("s_waitcnt lgkmcnt(0)\n\ts_barrier" ::: "memory")

// ---------------- K0: weight transpose to bf16 ----------------
__global__ __launch_bounds__(256) void k0_wt(const float* __restrict__ Wv,
                                             const float* __restrict__ WL,
                                             unsigned short* __restrict__ WvT,
                                             unsigned short* __restrict__ WLT) {
  int t = blockIdx.x * 256 + threadIdx.x;   // 16384 threads
  int c = t >> 8, i = t & 255;
  WvT[i * CH + c] = f2bu(Wv[c * INNER + i]);
  WLT[i * CH + c] = f2bu(WL[c * INNER + i]);
}

// ---------------- K1: channel Gram matrix ----------------
__global__ __launch_bounds__(256) void k1_xx(const float* __restrict__ x,
                                             float* __restrict__ xx) {
  const int b = blockIdx.y;
  const int wave = threadIdx.x >> 6, lane = threadIdx.x & 63;
  const int r = lane & 15, g = lane >> 4;
  const int gw = blockIdx.x * 4 + wave;   // 0..127 waves per b (gridDim.x == 32)
  const int per = NPOS / 128;             // 512 n per wave
  const size_t n0 = (size_t)gw * per;
  const float* xb = x + (size_t)b * CH * NPOS;

  facc acc[4][4] = {};

  for (int n = 0; n < per; n += 32) {
    bfrag fr[4];
#pragma unroll
    for (int t = 0; t < 4; ++t) {
      const float* p = xb + (size_t)(16 * t + r) * NPOS + n0 + n + g * 8;
      fvec4 lo = *(const fvec4*)p;
      fvec4 hi = *(const fvec4*)(p + 4);
      bfrag f;
#pragma unroll
      for (int e = 0; e < 4; ++e) { f[e] = (__bf16)lo[e]; f[e + 4] = (__bf16)hi[e]; }
      fr[t] = f;
    }
#pragma unroll
    for (int ti = 0; ti < 4; ++ti)
#pragma unroll
      for (int tj = 0; tj < 4; ++tj)
        acc[ti][tj] = __builtin_amdgcn_mfma_f32_16x16x32_bf16(fr[ti], fr[tj],
                                                              acc[ti][tj], 0, 0, 0);
  }

  __shared__ float red[4][4096];
  float* my = red[wave];
#pragma unroll
  for (int ti = 0; ti < 4; ++ti)
#pragma unroll
    for (int tj = 0; tj < 4; ++tj)
#pragma unroll
      for (int q = 0; q < 4; ++q)
        my[(16 * ti + g * 4 + q) * 64 + 16 * tj + r] = acc[ti][tj][q];
  __syncthreads();
  float* xxb = xx + (size_t)b * 4096;
  for (int i = threadIdx.x; i < 4096; i += 256)
    atomicAdd(xxb + i, red[0][i] + red[1][i] + red[2][i] + red[3][i]);
}

// ---------------- K2: MFMA finalize attention, fold Wp ----------------
__global__ __launch_bounds__(256) void k2_attn(
    const float* __restrict__ xx, const float* __restrict__ Wq,
    const float* __restrict__ Wk, const float* __restrict__ rescale,
    const float* __restrict__ Wp, unsigned short* __restrict__ Mt) {
  const int b = blockIdx.x >> 2, h = blockIdx.x & 3;
  const int t = threadIdx.x;
  const int wave = t >> 6, lane = t & 63;
  const int r = lane & 15, g = lane >> 4;

  __shared__ __align__(16) char tXX[8192];
  __shared__ __align__(16) char tWq[8192];
  __shared__ __align__(16) char tWk[8192];
  __shared__ __align__(16) char tWp[8192];
  __shared__ __align__(16) char tZq[8192];
  __shared__ __align__(16) char tZk[8192];
  __shared__ __align__(16) char tAt[8192];
  __shared__ float gG[64][68];
  __shared__ float sMx[64][4], sSm[64][4];
  __shared__ float sNq[64], sNk[64];

  const float* xxb = xx + (size_t)b * 4096;
#pragma unroll
  for (int rep = 0; rep < 16; ++rep) {
    int idx = rep * 256 + t;
    int row = idx >> 6, col = idx & 63;
    *(unsigned short*)(tXX + SWA(row, col * 2)) = f2bu(xxb[idx]);
    float vq = Wq[row * INNER + h * 64 + col];
    float vk = Wk[row * INNER + h * 64 + col];
    *(unsigned short*)(tWq + SWA(col, row * 2)) = f2bu(vq);
    *(unsigned short*)(tWk + SWA(col, row * 2)) = f2bu(vk);
    *(unsigned short*)(tWp + SWA(col, row * 2)) = f2bu(Wp[(h * 64 + row) * CH + col]);
  }
  __syncthreads();

  facc zq[4] = {}, zk[4] = {};
#pragma unroll
  for (int s = 0; s < 2; ++s) {
    bfrag aq = *(const bfrag*)(tWq + SWA(16 * wave + r, s * 64 + g * 16));
    bfrag ak = *(const bfrag*)(tWk + SWA(16 * wave + r, s * 64 + g * 16));
#pragma unroll
    for (int tj = 0; tj < 4; ++tj) {
      bfrag bx = *(const bfrag*)(tXX + SWA(16 * tj + r, s * 64 + g * 16));
      zq[tj] = __builtin_amdgcn_mfma_f32_16x16x32_bf16(aq, bx, zq[tj], 0, 0, 0);
      zk[tj] = __builtin_amdgcn_mfma_f32_16x16x32_bf16(ak, bx, zk[tj], 0, 0, 0);
    }
  }
#pragma unroll
  for (int tj = 0; tj < 4; ++tj)
#pragma unroll
    for (int q = 0; q < 4; ++q) {
      int row = 16 * wave + g * 4 + q, colb = (16 * tj + r) * 2;
      *(unsigned short*)(tZq + SWA(row, colb)) = f2bu(zq[tj][q]);
      *(unsigned short*)(tZk + SWA(row, colb)) = f2bu(zk[tj][q]);
    }
  __syncthreads();

  facc ga[4] = {}, q2[4] = {}, k2[4] = {};
#pragma unroll
  for (int s = 0; s < 2; ++s) {
    bfrag azk = *(const bfrag*)(tZk + SWA(16 * wave + r, s * 64 + g * 16));
    bfrag azq = *(const bfrag*)(tZq + SWA(16 * wave + r, s * 64 + g * 16));
#pragma unroll
    for (int tj = 0; tj < 4; ++tj) {
      bfrag bq = *(const bfrag*)(tWq + SWA(16 * tj + r, s * 64 + g * 16));
      bfrag bk = *(const bfrag*)(tWk + SWA(16 * tj + r, s * 64 + g * 16));
      ga[tj] = __builtin_amdgcn_mfma_f32_16x16x32_bf16(azk, bq, ga[tj], 0, 0, 0);
      q2[tj] = __builtin_amdgcn_mfma_f32_16x16x32_bf16(azq, bq, q2[tj], 0, 0, 0);
      k2[tj] = __builtin_amdgcn_mfma_f32_16x16x32_bf16(azk, bk, k2[tj], 0, 0, 0);
    }
  }
#pragma unroll
  for (int tj = 0; tj < 4; ++tj)
#pragma unroll
    for (int q = 0; q < 4; ++q) {
      int row = 16 * wave + g * 4 + q, col = 16 * tj + r;
      gG[row][col] = ga[tj][q];
      if (row == col) { sNq[row] = q2[tj][q]; sNk[row] = k2[tj][q]; }
    }
  __syncthreads();

  if (t < 64) {
    sNq[t] = 1.f / fmaxf(sqrtf(sNq[t]), 1e-12f);
    sNk[t] = rescale[h] / fmaxf(sqrtf(sNk[t]), 1e-12f);
  }
  __syncthreads();

  {
    const int d = t >> 2, p = t & 3;
    const float ik = sNk[d];
    float le[16];
    float mx = -1e30f;
#pragma unroll
    for (int j = 0; j < 16; ++j) {
      float v = gG[d][16 * p + j] * ik * sNq[16 * p + j];
      le[j] = v; mx = fmaxf(mx, v);
    }
    sMx[d][p] = mx;
    __syncthreads();
    mx = fmaxf(fmaxf(sMx[d][0], sMx[d][1]), fmaxf(sMx[d][2], sMx[d][3]));
    float sm = 0.f;
#pragma unroll
    for (int j = 0; j < 16; ++j) { le[j] = __expf(le[j] - mx); sm += le[j]; }
    sSm[d][p] = sm;
    __syncthreads();
    sm = sSm[d][0] + sSm[d][1] + sSm[d][2] + sSm[d][3];
    const float inv = 1.f / sm;
#pragma unroll
    for (int j = 0; j < 16; ++j) {
      int e = 16 * p + j;
      *(unsigned short*)(tAt + SWA(e, d * 2)) = f2bu(le[j] * inv);
    }
  }
  __syncthreads();

  facc m[4] = {};
#pragma unroll
  for (int s = 0; s < 2; ++s) {
    bfrag aa = *(const bfrag*)(tAt + SWA(16 * wave + r, s * 64 + g * 16));
#pragma unroll
    for (int tj = 0; tj < 4; ++tj) {
      bfrag bw = *(const bfrag*)(tWp + SWA(16 * tj + r, s * 64 + g * 16));
      m[tj] = __builtin_amdgcn_mfma_f32_16x16x32_bf16(aa, bw, m[tj], 0, 0, 0);
    }
  }
#pragma unroll
  for (int tj = 0; tj < 4; ++tj)
#pragma unroll
    for (int q = 0; q < 4; ++q) {
      int e = 16 * wave + g * 4 + q, c2 = 16 * tj + r;
      Mt[((size_t)(b * CH + c2)) * INNER + h * 64 + e] = f2bu(m[tj][q]);
    }
}

// ---------------- K3: gated V + folded output projection ----------------
// f32 tiles staged by global_load_lds (async DMA), source-quad swizzled so
// the per-(c,j) f32 reads are 2-way bank-free. Counted vmcnt(4); every
// wait+barrier pair fused into one asm volatile ("memory") so no LDS op can
// be scheduled between the wait and the barrier (round-9 race fix).
__global__ __launch_bounds__(256) void k3_out(
    const float* __restrict__ x, const float* __restrict__ illu,
    const unsigned short* __restrict__ WvT, const unsigned short* __restrict__ WLT,
    const unsigned short* __restrict__ Mt, const float* __restrict__ bp,
    float* __restrict__ out) {
  const int b = blockIdx.y;
  const int wave = threadIdx.x >> 6, lane = threadIdx.x & 63;
  const int r = lane & 15, g = lane >> 4;
  const int n0 = blockIdx.x * 256;          // gridDim.x == 256; 8 chunks of 32 n

  __shared__ __align__(16) float xf[2][64][32];   // x  f32 tile, quad-swizzled
  __shared__ __align__(16) float ifl[2][64][32];  // illu
  __shared__ __align__(16) char lvs[2][8192];     // v tile [j=16][i=256] bf16

  // --- per-wave weight fragments (A-operands), 16B vector loads ---
  bfrag wvA[4][2], wlA[4][2], mtA[8];
#pragma unroll
  for (int ti = 0; ti < 4; ++ti) {
    const int i = wave * 64 + ti * 16 + r;
#pragma unroll
    for (int s = 0; s < 2; ++s) {
      wvA[ti][s] = *(const bfrag*)(WvT + i * CH + s * 32 + g * 8);
      wlA[ti][s] = *(const bfrag*)(WLT + i * CH + s * 32 + g * 8);
    }
  }
#pragma unroll
  for (int s8 = 0; s8 < 8; ++s8)
    mtA[s8] = *(const bfrag*)(Mt + ((size_t)(b * CH + wave * 16 + r)) * INNER + s8 * 32 + g * 8);
  float bcol[4];
#pragma unroll
  for (int q = 0; q < 4; ++q) bcol[q] = bp[wave * 16 + g * 4 + q];

  const float* xb = x + (size_t)b * CH * NPOS;
  const float* ib = illu + (size_t)b * CH * NPOS;
  float* ob = out + (size_t)b * CH * NPOS;

  // DMA per-lane source offsets: inst covers rows wave*16+.., lane covers
  // row c = base + lane/8, n-quad (lane&7) ^ FK(c).
  const int c0 = wave * 16 + (lane >> 3);
  const int c1 = c0 + 8;
  const int k0_ = (c0 >> 3) & 3, k1_ = (c1 >> 3) & 3;
  const int fk0 = k0_ ^ ((k0_ & 1) << 2), fk1 = k1_ ^ ((k1_ & 1) << 2);
  const size_t off0 = (size_t)c0 * NPOS + (((lane & 7) ^ fk0) << 2);
  const size_t off1 = (size_t)c1 * NPOS + (((lane & 7) ^ fk1) << 2);

#define ISSUE(BUF, NC)                                                        \
  {                                                                           \
    __builtin_amdgcn_global_load_lds((guint*)(xb + off0 + (NC)),              \
        (luint*)&xf[BUF][wave * 16][0], 16, 0, 0);                            \
    __builtin_amdgcn_global_load_lds((guint*)(xb + off1 + (NC)),              \
        (luint*)&xf[BUF][wave * 16 + 8][0], 16, 0, 0);                        \
    __builtin_amdgcn_global_load_lds((guint*)(ib + off0 + (NC)),              \
        (luint*)&ifl[BUF][wave * 16][0], 16, 0, 0);                           \
    __builtin_amdgcn_global_load_lds((guint*)(ib + off1 + (NC)),              \
        (luint*)&ifl[BUF][wave * 16 + 8][0], 16, 0, 0);                       \
  }

  // prologue: chunk 0 into buf 0 (full drain OK here, once)
  ISSUE(0, n0);
  BAR_VM0();

  const int fkr = g ^ ((g & 1) << 2);   // read-side key (= FK of the 8 c's read)

  for (int cc = 0; cc < 8; ++cc) {
    const int cb = cc & 1;
    const int nbase = n0 + cc * 32;
    if (cc < 7) ISSUE(cb ^ 1, nbase + 32);
    BAR_VM4();                          // buf cb's DMA landed, all waves

#pragma unroll 2
    for (int sub = 0; sub < 2; ++sub) {
      const int j0 = sub * 16;
      const int j = j0 + r;
      const int qw = ((((j >> 2) ^ fkr) << 2) | (j & 3));   // word in row
      // ---- build B-fragments from f32 LDS (2-way bank-free) ----
      bfrag xB[2], iB[2];
#pragma unroll
      for (int s = 0; s < 2; ++s) {
        float xw[8], iw[8];
#pragma unroll
        for (int e = 0; e < 8; ++e) {
          const int c = s * 32 + g * 8 + e;
          xw[e] = xf[cb][c][qw];
          iw[e] = ifl[cb][c][qw];
        }
        bfrag fx, fi;
#pragma unroll
        for (int e = 0; e < 8; ++e) { fx[e] = (__bf16)xw[e]; fi[e] = (__bf16)iw[e]; }
        xB[s] = fx; iB[s] = fi;
      }
      facc av[4] = {}, gv[4] = {};
      __builtin_amdgcn_s_setprio(1);
#pragma unroll
      for (int ti = 0; ti < 4; ++ti) {
#pragma unroll
        for (int s = 0; s < 2; ++s) {
          av[ti] = __builtin_amdgcn_mfma_f32_16x16x32_bf16(wvA[ti][s], xB[s], av[ti], 0, 0, 0);
          gv[ti] = __builtin_amdgcn_mfma_f32_16x16x32_bf16(wlA[ti][s], iB[s], gv[ti], 0, 0, 0);
        }
      }
      __builtin_amdgcn_s_setprio(0);
      // gate + packed b64 write of v tile
#pragma unroll
      for (int ti = 0; ti < 4; ++ti) {
        const float v0 = av[ti][0] * gv[ti][0], v1 = av[ti][1] * gv[ti][1];
        const float v2 = av[ti][2] * gv[ti][2], v3 = av[ti][3] * gv[ti][3];
        const int i = wave * 64 + ti * 16 + g * 4;
        const int sw = (r & 7) << 4;
        unsigned long long pk =
            (unsigned long long)((unsigned int)f2bu(v0) | ((unsigned int)f2bu(v1) << 16)) |
            ((unsigned long long)((unsigned int)f2bu(v2) | ((unsigned int)f2bu(v3) << 16)) << 32);
        *(unsigned long long*)(lvs[sub] + r * 512 + ((i * 2) ^ sw)) = pk;
      }
      BAR_LGKM();                       // v tile complete (vmcnt stays in flight)
      // out tile: M^T @ v  (K = i = 256)
      facc ov = {0.f, 0.f, 0.f, 0.f};
      __builtin_amdgcn_s_setprio(1);
#pragma unroll
      for (int s8 = 0; s8 < 8; ++s8) {
        const int byte = (s8 * 64 + g * 16) ^ ((r & 7) << 4);
        bfrag vB = *(const bfrag*)(lvs[sub] + r * 512 + byte);
        ov = __builtin_amdgcn_mfma_f32_16x16x32_bf16(mtA[s8], vB, ov, 0, 0, 0);
      }
      __builtin_amdgcn_s_setprio(0);
#pragma unroll
      for (int q = 0; q < 4; ++q)
        ob[(size_t)(wave * 16 + g * 4 + q) * NPOS + nbase + j0 + r] = ov[q] + bcol[q];
    }
  }
#undef ISSUE
}

extern "C" void kernel_launch(void* const* d_in, const int* in_sizes, int n_in,
                              void* d_out, int out_size, void* d_ws, size_t ws_size,
                              hipStream_t stream) {
  (void)in_sizes; (void)n_in; (void)out_size; (void)ws_size;
  const float* x    = (const float*)d_in[0];
  const float* illu = (const float*)d_in[1];
  const float* Wq   = (const float*)d_in[2];
  const float* Wk   = (const float*)d_in[3];
  const float* Wv   = (const float*)d_in[4];
  const float* WL   = (const float*)d_in[5];
  const float* rsc  = (const float*)d_in[6];
  const float* Wp   = (const float*)d_in[7];
  const float* bp   = (const float*)d_in[8];
  float* out = (float*)d_out;

  float* xxws = (float*)d_ws;                                        // 64 KB
  unsigned short* Mt  = (unsigned short*)((char*)d_ws + 65536);      // 128 KB
  unsigned short* WvT = (unsigned short*)((char*)d_ws + 65536 + 131072); // 32 KB
  unsigned short* WLT = WvT + INNER * CH;                            // 32 KB

  hipMemsetAsync(d_ws, 0, (size_t)4 * 4096 * sizeof(float), stream);
  hipLaunchKernelGGL(k0_wt, dim3(64), dim3(256), 0, stream, Wv, WL, WvT, WLT);
  hipLaunchKernelGGL(k1_xx, dim3(32, 4), dim3(256), 0, stream, x, xxws);
  hipLaunchKernelGGL(k2_attn, dim3(16), dim3(256), 0, stream, xxws, Wq, Wk, rsc, Wp, Mt);
  hipLaunchKernelGGL(k3_out, dim3(256, 4), dim3(256), 0, stream, x, illu, WvT, WLT, Mt, bp, out);
}